// Round 10
// baseline (248.834 us; speedup 1.0000x reference)
//
#include <hip/hip_runtime.h>
#include <hip/hip_bf16.h>
#include <math.h>

typedef float  f32x4 __attribute__((ext_vector_type(4)));
typedef short  s16x8 __attribute__((ext_vector_type(8)));
typedef unsigned short u16x4 __attribute__((ext_vector_type(4)));
typedef unsigned u32x4 __attribute__((ext_vector_type(4)));

// ---------- helpers ----------
__device__ __forceinline__ unsigned short f2bf(float f) {
  unsigned u = __float_as_uint(f);
  u += 0x7FFFu + ((u >> 16) & 1u);   // round-to-nearest-even
  return (unsigned short)(u >> 16);
}
// packed f32x8 -> bf16x8 via v_cvt_pk_bf16_f32 (compiler-generated)
__device__ __forceinline__ u32x4 cvt8(f32x4 a, f32x4 b) {
  union { __hip_bfloat162 h; unsigned u; } c0, c1, c2, c3;
  c0.h = __float22bfloat162_rn(float2{a[0], a[1]});
  c1.h = __float22bfloat162_rn(float2{a[2], a[3]});
  c2.h = __float22bfloat162_rn(float2{b[0], b[1]});
  c3.h = __float22bfloat162_rn(float2{b[2], b[3]});
  u32x4 o; o[0] = c0.u; o[1] = c1.u; o[2] = c2.u; o[3] = c3.u;
  return o;
}
// monotone float->uint encoding, biased so enc2(-inf)==0 (zero-init-friendly)
__device__ __forceinline__ unsigned fenc2(float f) {
  unsigned u = __float_as_uint(f);
  u = (u & 0x80000000u) ? ~u : (u | 0x80000000u);
  return u - 0x007FFFFFu;
}
__device__ __forceinline__ float fdec2(unsigned u) {
  u += 0x007FFFFFu;
  u = (u & 0x80000000u) ? (u & 0x7FFFFFFFu) : ~u;
  return __uint_as_float(u);
}
__device__ __forceinline__ void gload16(const void* g, void* l) {
  __builtin_amdgcn_global_load_lds(
      (const __attribute__((address_space(1))) unsigned int*)g,
      (__attribute__((address_space(3))) unsigned int*)l, 16, 0, 0);
}

// ---------- weights f32 -> bf16 + zero the init zone (one launch) ----------
__global__ __launch_bounds__(256) void cvt2w(const float* __restrict__ a,
                                             const float* __restrict__ b,
                                             unsigned short* __restrict__ da,
                                             unsigned short* __restrict__ db,
                                             unsigned* __restrict__ initzone) {
  const int n4 = 147456;
  int i = blockIdx.x * 256 + threadIdx.x;
  int stride = gridDim.x * 256;
  if (i < 49152) initzone[i] = 0;   // um + qss + kss
  for (; i < 2 * n4; i += stride) {
    const float* s = (i < n4) ? a : b;
    unsigned short* d = (i < n4) ? da : db;
    int j = (i < n4) ? i : i - n4;
    f32x4 v = ((const f32x4*)s)[j];
    u16x4 o;
    o[0] = f2bf(v[0]); o[1] = f2bf(v[1]); o[2] = f2bf(v[2]); o[3] = f2bf(v[3]);
    ((u16x4*)d)[j] = o;
  }
}

// ---------- proj (unchanged, round-8 measured 91us) ----------
__global__ __launch_bounds__(256) void proj(const float* __restrict__ Xq,
                                            const float* __restrict__ Xk,
                                            const unsigned short* __restrict__ Wqb,
                                            const unsigned short* __restrict__ Wkb,
                                            const float* __restrict__ bq,
                                            const float* __restrict__ bk,
                                            unsigned short* __restrict__ Qh,
                                            unsigned short* __restrict__ Kh,
                                            float* __restrict__ qssq,
                                            float* __restrict__ kssq) {
  const int K = 768;
  __shared__ __align__(16) unsigned short sA[128 * 64];
  __shared__ __align__(16) unsigned short sB[128 * 64];
  int id = blockIdx.x;                 // 0..767
  int xcd = id & 7, j = id >> 3;       // j: 0..95
  int by = j % 6, bxl = j / 6;         // by 0..5, bxl 0..15
  int bx = xcd * 16 + bxl;             // 0..127
  const float* A; const unsigned short* Bw; const float* bias;
  unsigned short* Out; float* ssq;
  if (blockIdx.z == 0) { A = Xq; Bw = Wqb; bias = bq; Out = Qh; ssq = qssq; }
  else                 { A = Xk; Bw = Wkb; bias = bk; Out = Kh; ssq = kssq; }

  const int t = threadIdx.x;
  const int lane = t & 63, w = t >> 6;
  const int wr = w >> 1, wc = w & 1;
  const int m0 = bx * 128, n0 = by * 128;
  const float* Ab = A + (size_t)m0 * K;
  const unsigned short* Bb = Bw + (size_t)n0 * K;
  f32x4 acc[4][4] = {};
  const int srow = t >> 3;             // 0..31
  const int scol = (t & 7) * 8;        // halfword col offset in 64
  const int hsw = scol ^ ((srow & 7) << 3);
  const int lg = lane >> 4, li = lane & 15;

  for (int k0 = 0; k0 < K; k0 += 64) {
#pragma unroll
    for (int s = 0; s < 4; ++s) {
      int row = srow + s * 32;
      gload16(Bb + (size_t)row * K + k0 + hsw, (char*)sB + t * 16 + s * 4096);
    }
#pragma unroll
    for (int s = 0; s < 4; ++s) {
      int row = srow + s * 32;
      const float* src = Ab + (size_t)row * K + k0 + scol;
      f32x4 v0 = *(const f32x4*)(src);
      f32x4 v1 = *(const f32x4*)(src + 4);
      *(u32x4*)(sA + row * 64 + (scol ^ ((row & 7) << 3))) = cvt8(v0, v1);
    }
    __syncthreads();
#pragma unroll
    for (int ks = 0; ks < 2; ++ks) {
      s16x8 af[4], bfr[4];
#pragma unroll
      for (int mi = 0; mi < 4; ++mi) {
        int row = wr * 64 + mi * 16 + li;
        af[mi] = *(const s16x8*)(sA + row * 64 + ((ks * 32 + lg * 8) ^ ((row & 7) << 3)));
      }
#pragma unroll
      for (int ni = 0; ni < 4; ++ni) {
        int row = wc * 64 + ni * 16 + li;
        bfr[ni] = *(const s16x8*)(sB + row * 64 + ((ks * 32 + lg * 8) ^ ((row & 7) << 3)));
      }
#pragma unroll
      for (int mi = 0; mi < 4; ++mi)
#pragma unroll
        for (int ni = 0; ni < 4; ++ni)
          acc[mi][ni] = __builtin_amdgcn_mfma_f32_16x16x32_bf16(af[mi], bfr[ni], acc[mi][ni], 0, 0, 0);
    }
    __syncthreads();
  }
  float bv[4]; int col[4];
#pragma unroll
  for (int ni = 0; ni < 4; ++ni) { col[ni] = n0 + wc * 64 + ni * 16 + li; bv[ni] = bias[col[ni]]; }
#pragma unroll
  for (int mi = 0; mi < 4; ++mi) {
    int rbase = m0 + wr * 64 + mi * 16 + lg * 4;
#pragma unroll
    for (int r = 0; r < 4; ++r) {
      float s = 0.f;
#pragma unroll
      for (int ni = 0; ni < 4; ++ni) {
        float v = acc[mi][ni][r] + bv[ni];
        Out[(size_t)(rbase + r) * 768 + col[ni]] = f2bf(v);
        s += v * v;
      }
#pragma unroll
      for (int off = 1; off < 16; off <<= 1) s += __shfl_xor(s, off, 64);
      if (li == 0) atomicAdd(&ssq[rbase + r], s);
    }
  }
}

// ---------- scores: 4-slot depth-3 counted-vmcnt pipeline (T4), 512 thr ----------
// 128^2 tile, BK=64, 8 waves (wave-tile 64x32), 4 LDS slots (128KB, 1 block/CU).
// Pipeline proof: iter t issues STAGE(t+3) into slot (t+3)&3 == slot (t-1)&3,
// whose reads finished before barrier B(t-1) (issue is after B(t-1)).  Each wave's
// vmcnt(8) at end of iter t retires its 4 oldest loads (= K-tile t+1, issued 3
// iters earlier); the following s_barrier makes that guarantee cross-wave, so
// iter t+1's ds_reads see a fully-landed slot.  vmcnt never drains to 0 in the
// steady state (t+2, t+3 stay in flight across the barrier).
__global__ __launch_bounds__(512, 1) void scores_max(const unsigned short* __restrict__ Qh,
                                                     const unsigned short* __restrict__ Kh,
                                                     const float* __restrict__ kssq,
                                                     const int* __restrict__ pad,
                                                     unsigned* __restrict__ umax) {
  const int K = 768;
  __shared__ __align__(16) unsigned short sA[4][128 * 64];
  __shared__ __align__(16) unsigned short sB[4][128 * 64];
  // batch -> XCD pinning: id&7 == batch&7 (unchanged mapping)
  int id = blockIdx.x;                 // 0..1023
  int x = id & 7, g = id >> 3;
  int tile = g & 63;
  int qt = tile & 7, kt_ = tile >> 3;
  int b = ((g >> 6) << 3) | x;

  const int t = threadIdx.x;           // 0..511
  const int lane = t & 63, w = t >> 6; // 8 waves
  const int wr = w >> 2, wcn = w & 3;  // 2M x 4N
  const unsigned short* Ab = Qh + ((size_t)b * 1024 + qt * 128) * K;
  const unsigned short* Bb = Kh + ((size_t)b * 1024 + kt_ * 128) * K;
  f32x4 acc[4][2] = {};
  const int lg = lane >> 4, li = lane & 15;
  // staging geometry: idx = s*512 + t (s=0,1); row = idx>>3; col8 = (idx&7)*8
  const int r0 = t >> 3;               // rows 0..63
  const int r1 = (512 + t) >> 3;       // rows 64..127
  const int c8 = (t & 7) * 8;
  const int sc0 = c8 ^ ((r0 & 7) << 3);   // pre-swizzled source col (halfwords)
  const int sc1 = c8 ^ ((r1 & 7) << 3);

#define STAGE(KT)                                                              \
  {                                                                            \
    const int _s = (KT) & 3;                                                   \
    gload16(Ab + (size_t)r0 * K + (KT) * 64 + sc0, (char*)sA[_s] + t * 16);    \
    gload16(Ab + (size_t)r1 * K + (KT) * 64 + sc1, (char*)sA[_s] + 8192 + t * 16); \
    gload16(Bb + (size_t)r0 * K + (KT) * 64 + sc0, (char*)sB[_s] + t * 16);    \
    gload16(Bb + (size_t)r1 * K + (KT) * 64 + sc1, (char*)sB[_s] + 8192 + t * 16); \
  }

  // prologue: K-tiles 0,1,2 in flight; wait until tile 0 landed (8 = tiles 1,2)
  STAGE(0); STAGE(1); STAGE(2);
  asm volatile("s_waitcnt vmcnt(8)" ::: "memory");
  __builtin_amdgcn_s_barrier();
  __builtin_amdgcn_sched_barrier(0);

#pragma unroll
  for (int kt = 0; kt < 12; ++kt) {
    if (kt + 3 < 12) STAGE(kt + 3);
    __builtin_amdgcn_sched_barrier(0);   // pin: stage-issue before compute
    const unsigned short* cA = sA[kt & 3];
    const unsigned short* cB = sB[kt & 3];
#pragma unroll
    for (int ks = 0; ks < 2; ++ks) {
      s16x8 af[4], bfr[2];
#pragma unroll
      for (int mi = 0; mi < 4; ++mi) {
        int row = wr * 64 + mi * 16 + li;
        af[mi] = *(const s16x8*)(cA + row * 64 + ((ks * 32 + lg * 8) ^ ((row & 7) << 3)));
      }
#pragma unroll
      for (int ni = 0; ni < 2; ++ni) {
        int row = wcn * 32 + ni * 16 + li;
        bfr[ni] = *(const s16x8*)(cB + row * 64 + ((ks * 32 + lg * 8) ^ ((row & 7) << 3)));
      }
      __builtin_amdgcn_s_setprio(1);
#pragma unroll
      for (int mi = 0; mi < 4; ++mi)
#pragma unroll
        for (int ni = 0; ni < 2; ++ni)
          acc[mi][ni] = __builtin_amdgcn_mfma_f32_16x16x32_bf16(af[mi], bfr[ni], acc[mi][ni], 0, 0, 0);
      __builtin_amdgcn_s_setprio(0);
    }
    // counted waits: ensure K-tile kt+1 landed; keep kt+2/kt+3 in flight
    if (kt < 9)        asm volatile("s_waitcnt vmcnt(8)" ::: "memory");
    else if (kt == 9)  asm volatile("s_waitcnt vmcnt(4)" ::: "memory");
    else if (kt == 10) asm volatile("s_waitcnt vmcnt(0)" ::: "memory");
    if (kt < 11) {
      __builtin_amdgcn_s_barrier();
      __builtin_amdgcn_sched_barrier(0);
    }
  }
#undef STAGE

  // epilogue: 1/||k|| col scaling, pad mask, row max, atomicMax (enc2)
  float rk[2]; bool valid[2];
#pragma unroll
  for (int ni = 0; ni < 2; ++ni) {
    int gcol = b * 1024 + kt_ * 128 + wcn * 32 + ni * 16 + li;
    rk[ni] = 1.0f / fmaxf(sqrtf(kssq[gcol]), 1e-8f);
    valid[ni] = (pad[gcol] == 0);
  }
#pragma unroll
  for (int mi = 0; mi < 4; ++mi) {
#pragma unroll
    for (int r = 0; r < 4; ++r) {
      float v = -INFINITY;
#pragma unroll
      for (int ni = 0; ni < 2; ++ni)
        if (valid[ni]) v = fmaxf(v, acc[mi][ni][r] * rk[ni]);
#pragma unroll
      for (int off = 1; off < 16; off <<= 1) v = fmaxf(v, __shfl_xor(v, off, 64));
      if (li == 0) {
        int row = b * 1024 + qt * 128 + wr * 64 + mi * 16 + lg * 4 + r;
        unsigned e = fenc2(v);
        if (e) atomicMax(&umax[row], e);
      }
    }
  }
}

// ---------- tiny MLP ----------
__global__ __launch_bounds__(256) void mlp_kernel(const unsigned* __restrict__ umax,
                                                  const float* __restrict__ qssq,
                                                  const float* __restrict__ w1,
                                                  const float* __restrict__ b1,
                                                  const float* __restrict__ w2,
                                                  const float* __restrict__ b2,
                                                  float* __restrict__ out, int n) {
  int i = blockIdx.x * 256 + threadIdx.x;
  if (i >= n) return;
  float m = fdec2(umax[i]) / fmaxf(sqrtf(qssq[i]), 1e-8f);
  float s = b2[0];
#pragma unroll
  for (int j = 0; j < 16; ++j) s += w2[j] * fmaxf(m * w1[j] + b1[j], 0.f);
  out[i] = 1.f / (1.f + expf(-s));
}

// ---------- host ----------
extern "C" void kernel_launch(void* const* d_in, const int* in_sizes, int n_in,
                              void* d_out, int out_size, void* d_ws, size_t ws_size,
                              hipStream_t stream) {
  const float* image = (const float*)d_in[0];   // [16,32,32,768]
  const float* text  = (const float*)d_in[1];   // [16,1024,768]
  const int*   pad   = (const int*)d_in[2];     // [16,32,32]
  const float* Wq    = (const float*)d_in[3];
  const float* bq    = (const float*)d_in[4];
  const float* Wk    = (const float*)d_in[5];
  const float* bk    = (const float*)d_in[6];
  const float* W1    = (const float*)d_in[7];
  const float* b1    = (const float*)d_in[8];
  const float* W2    = (const float*)d_in[9];
  const float* b2    = (const float*)d_in[10];
  float* out = (float*)d_out;

  char* ws = (char*)d_ws;
  unsigned*       um  = (unsigned*)(ws);                    // 65536
  float*          qss = (float*)(ws + 65536);               // 65536
  float*          kss = (float*)(ws + 131072);              // 65536
  unsigned short* Wqb = (unsigned short*)(ws + 196608);     // 1179648
  unsigned short* Wkb = (unsigned short*)(ws + 1376256);    // 1179648
  unsigned short* Qh  = (unsigned short*)(ws + 2555904);    // 25165824
  unsigned short* Kh  = (unsigned short*)(ws + 27721728);   // 25165824

  // 1) weights -> bf16, zero um/qss/kss
  cvt2w<<<1152, 256, 0, stream>>>(Wq, Wk, Wqb, Wkb, um);
  // 2) both projections (fused f32->bf16 A-staging), one dispatch
  proj<<<dim3(768, 1, 2), 256, 0, stream>>>(text, image, Wqb, Wkb, bq, bk, Qh, Kh, qss, kss);
  // 3) masked cosine scores + row max (pipelined)
  scores_max<<<1024, 512, 0, stream>>>(Qh, Kh, kss, pad, um);
  // 4) tiny MLP
  mlp_kernel<<<64, 256, 0, stream>>>(um, qss, W1, b1, W2, b2, out, 16384);
}

// Round 11
// 238.689 us; speedup vs baseline: 1.0425x; 1.0425x over previous
//
#include <hip/hip_runtime.h>
#include <hip/hip_bf16.h>
#include <math.h>

typedef float  f32x4 __attribute__((ext_vector_type(4)));
typedef short  s16x8 __attribute__((ext_vector_type(8)));
typedef unsigned short u16x4 __attribute__((ext_vector_type(4)));
typedef unsigned u32x4 __attribute__((ext_vector_type(4)));

// ---------- helpers ----------
__device__ __forceinline__ unsigned short f2bf(float f) {
  unsigned u = __float_as_uint(f);
  u += 0x7FFFu + ((u >> 16) & 1u);   // round-to-nearest-even
  return (unsigned short)(u >> 16);
}
// packed f32x8 -> bf16x8 via v_cvt_pk_bf16_f32 (compiler-generated)
__device__ __forceinline__ u32x4 cvt8(f32x4 a, f32x4 b) {
  union { __hip_bfloat162 h; unsigned u; } c0, c1, c2, c3;
  c0.h = __float22bfloat162_rn(float2{a[0], a[1]});
  c1.h = __float22bfloat162_rn(float2{a[2], a[3]});
  c2.h = __float22bfloat162_rn(float2{b[0], b[1]});
  c3.h = __float22bfloat162_rn(float2{b[2], b[3]});
  u32x4 o; o[0] = c0.u; o[1] = c1.u; o[2] = c2.u; o[3] = c3.u;
  return o;
}
// monotone float->uint encoding, biased so enc2(-inf)==0 (zero-init-friendly)
__device__ __forceinline__ unsigned fenc2(float f) {
  unsigned u = __float_as_uint(f);
  u = (u & 0x80000000u) ? ~u : (u | 0x80000000u);
  return u - 0x007FFFFFu;
}
__device__ __forceinline__ float fdec2(unsigned u) {
  u += 0x007FFFFFu;
  u = (u & 0x80000000u) ? (u & 0x7FFFFFFFu) : ~u;
  return __uint_as_float(u);
}
__device__ __forceinline__ void gload16(const void* g, void* l) {
  __builtin_amdgcn_global_load_lds(
      (const __attribute__((address_space(1))) unsigned int*)g,
      (__attribute__((address_space(3))) unsigned int*)l, 16, 0, 0);
}

// ---------- weights f32 -> bf16 + zero the init zone (one launch) ----------
__global__ __launch_bounds__(256) void cvt2w(const float* __restrict__ a,
                                             const float* __restrict__ b,
                                             unsigned short* __restrict__ da,
                                             unsigned short* __restrict__ db,
                                             unsigned* __restrict__ initzone) {
  const int n4 = 147456;
  int i = blockIdx.x * 256 + threadIdx.x;
  int stride = gridDim.x * 256;
  if (i < 49152) initzone[i] = 0;   // um + qss + kss
  for (; i < 2 * n4; i += stride) {
    const float* s = (i < n4) ? a : b;
    unsigned short* d = (i < n4) ? da : db;
    int j = (i < n4) ? i : i - n4;
    f32x4 v = ((const f32x4*)s)[j];
    u16x4 o;
    o[0] = f2bf(v[0]); o[1] = f2bf(v[1]); o[2] = f2bf(v[2]); o[3] = f2bf(v[3]);
    ((u16x4*)d)[j] = o;
  }
}

// ---------- proj: Out = bf16(Xf32 @ W^T + bias), ssq[row] += sum of squares ----------
// Round-8 skeleton + cross-iteration A-prefetch (T14, sched_barrier-pinned) and
// raw s_barrier + counted vmcnt.  Per-iter wave ledger:
//   [outstanding: A(kt)=8 older]  issue B(kt) x4 gload_lds  -> 12
//   cvt A(kt): compiler waits vmcnt(4)  (retires the 8 A-loads)
//   issue A(kt+1) x8 (pinned)  -> 12
//   s_waitcnt vmcnt(8) lgkmcnt(0)  (retires B(kt); A(kt+1) stays in flight)
//   s_barrier ; compute ; s_barrier      <- A(kt+1) lands under compute
__global__ __launch_bounds__(256) void proj(const float* __restrict__ Xq,
                                            const float* __restrict__ Xk,
                                            const unsigned short* __restrict__ Wqb,
                                            const unsigned short* __restrict__ Wkb,
                                            const float* __restrict__ bq,
                                            const float* __restrict__ bk,
                                            unsigned short* __restrict__ Qh,
                                            unsigned short* __restrict__ Kh,
                                            float* __restrict__ qssq,
                                            float* __restrict__ kssq) {
  const int K = 768;
  __shared__ __align__(16) unsigned short sA[128 * 64];
  __shared__ __align__(16) unsigned short sB[128 * 64];
  int id = blockIdx.x;                 // 0..767
  int xcd = id & 7, j = id >> 3;       // j: 0..95
  int by = j % 6, bxl = j / 6;         // by 0..5, bxl 0..15
  int bx = xcd * 16 + bxl;             // 0..127
  const float* A; const unsigned short* Bw; const float* bias;
  unsigned short* Out; float* ssq;
  if (blockIdx.z == 0) { A = Xq; Bw = Wqb; bias = bq; Out = Qh; ssq = qssq; }
  else                 { A = Xk; Bw = Wkb; bias = bk; Out = Kh; ssq = kssq; }

  const int t = threadIdx.x;
  const int lane = t & 63, w = t >> 6;
  const int wr = w >> 1, wc = w & 1;
  const int m0 = bx * 128, n0 = by * 128;
  const float* Ab = A + (size_t)m0 * K;
  const unsigned short* Bb = Bw + (size_t)n0 * K;
  f32x4 acc[4][4] = {};
  const int srow = t >> 3;             // 0..31
  const int scol = (t & 7) * 8;        // halfword col offset in 64
  const int hsw = scol ^ ((srow & 7) << 3);
  const int lg = lane >> 4, li = lane & 15;

  f32x4 pa0[4], pa1[4];
  // prologue: issue A(0) f32 loads, pin issue point
#pragma unroll
  for (int s = 0; s < 4; ++s) {
    const float* src = Ab + (size_t)(srow + s * 32) * K + scol;
    pa0[s] = *(const f32x4*)src; pa1[s] = *(const f32x4*)(src + 4);
  }
  __builtin_amdgcn_sched_barrier(0);

#pragma unroll
  for (int kt = 0; kt < 12; ++kt) {
    const int k0 = kt * 64;
    // stage B(kt) (async to LDS) — safe: previous compute ended at loop-bottom barrier
#pragma unroll
    for (int s = 0; s < 4; ++s) {
      int row = srow + s * 32;
      gload16(Bb + (size_t)row * K + k0 + hsw, (char*)sB + t * 16 + s * 4096);
    }
    // cvt A(kt) -> swizzled ds_write (compiler inserts vmcnt(4) here: retires A(kt))
#pragma unroll
    for (int s = 0; s < 4; ++s) {
      int row = srow + s * 32;
      *(u32x4*)(sA + row * 64 + (scol ^ ((row & 7) << 3))) = cvt8(pa0[s], pa1[s]);
    }
    // issue A(kt+1), pinned above the barrier so it flies during compute(kt)
    if (kt < 11) {
      const int k0n = k0 + 64;
#pragma unroll
      for (int s = 0; s < 4; ++s) {
        const float* src = Ab + (size_t)(srow + s * 32) * K + k0n + scol;
        pa0[s] = *(const f32x4*)src; pa1[s] = *(const f32x4*)(src + 4);
      }
      __builtin_amdgcn_sched_barrier(0);
      asm volatile("s_waitcnt vmcnt(8) lgkmcnt(0)" ::: "memory");  // B(kt) landed; A(kt+1) in flight
    } else {
      __builtin_amdgcn_sched_barrier(0);
      asm volatile("s_waitcnt vmcnt(0) lgkmcnt(0)" ::: "memory");  // tail drain
    }
    __builtin_amdgcn_s_barrier();
    __builtin_amdgcn_sched_barrier(0);
    // compute tile kt
#pragma unroll
    for (int ks = 0; ks < 2; ++ks) {
      s16x8 af[4], bfr[4];
#pragma unroll
      for (int mi = 0; mi < 4; ++mi) {
        int row = wr * 64 + mi * 16 + li;
        af[mi] = *(const s16x8*)(sA + row * 64 + ((ks * 32 + lg * 8) ^ ((row & 7) << 3)));
      }
#pragma unroll
      for (int ni = 0; ni < 4; ++ni) {
        int row = wc * 64 + ni * 16 + li;
        bfr[ni] = *(const s16x8*)(sB + row * 64 + ((ks * 32 + lg * 8) ^ ((row & 7) << 3)));
      }
      __builtin_amdgcn_s_setprio(1);
#pragma unroll
      for (int mi = 0; mi < 4; ++mi)
#pragma unroll
        for (int ni = 0; ni < 4; ++ni)
          acc[mi][ni] = __builtin_amdgcn_mfma_f32_16x16x32_bf16(af[mi], bfr[ni], acc[mi][ni], 0, 0, 0);
      __builtin_amdgcn_s_setprio(0);
    }
    // end-of-iter barrier: all waves done reading sA/sB before next overwrite
    asm volatile("s_waitcnt lgkmcnt(0)" ::: "memory");
    __builtin_amdgcn_s_barrier();
    __builtin_amdgcn_sched_barrier(0);
  }
  // epilogue: bias, bf16 store, per-row sum-of-squares -> atomicAdd
  float bv[4]; int col[4];
#pragma unroll
  for (int ni = 0; ni < 4; ++ni) { col[ni] = n0 + wc * 64 + ni * 16 + li; bv[ni] = bias[col[ni]]; }
#pragma unroll
  for (int mi = 0; mi < 4; ++mi) {
    int rbase = m0 + wr * 64 + mi * 16 + lg * 4;
#pragma unroll
    for (int r = 0; r < 4; ++r) {
      float s = 0.f;
#pragma unroll
      for (int ni = 0; ni < 4; ++ni) {
        float v = acc[mi][ni][r] + bv[ni];
        Out[(size_t)(rbase + r) * 768 + col[ni]] = f2bf(v);
        s += v * v;
      }
#pragma unroll
      for (int off = 1; off < 16; off <<= 1) s += __shfl_xor(s, off, 64);
      if (li == 0) atomicAdd(&ssq[rbase + r], s);
    }
  }
}

// ---------- scores: round-6/8 proven 2-phase version (measured 45.5us) ----------
__global__ __launch_bounds__(256) void scores_max(const unsigned short* __restrict__ Qh,
                                                  const unsigned short* __restrict__ Kh,
                                                  const float* __restrict__ kssq,
                                                  const int* __restrict__ pad,
                                                  unsigned* __restrict__ umax) {
  const int K = 768;
  __shared__ __align__(16) unsigned short sA[128 * 64];
  __shared__ __align__(16) unsigned short sB[128 * 64];
  // batch -> XCD pinning: id&7 == batch&7
  int id = blockIdx.x;                 // 0..1023
  int x = id & 7, g = id >> 3;
  int tile = g & 63;
  int qt = tile & 7, kt_ = tile >> 3;
  int b = ((g >> 6) << 3) | x;

  const int t = threadIdx.x;
  const int lane = t & 63, w = t >> 6;
  const int wr = w >> 1, wc = w & 1;
  const unsigned short* Ab = Qh + ((size_t)b * 1024 + qt * 128) * K;
  const unsigned short* Bb = Kh + ((size_t)b * 1024 + kt_ * 128) * K;
  f32x4 acc[4][4] = {};
  const int srow = t >> 3;
  const int scol = (t & 7) * 8;
  const int hsw = scol ^ ((srow & 7) << 3);
  const int lg = lane >> 4, li = lane & 15;

  for (int k0 = 0; k0 < K; k0 += 64) {
#pragma unroll
    for (int s = 0; s < 4; ++s) {
      int row = srow + s * 32;
      gload16(Ab + (size_t)row * K + k0 + hsw, (char*)sA + t * 16 + s * 4096);
      gload16(Bb + (size_t)row * K + k0 + hsw, (char*)sB + t * 16 + s * 4096);
    }
    __syncthreads();
#pragma unroll
    for (int ks = 0; ks < 2; ++ks) {
      s16x8 af[4], bfr[4];
#pragma unroll
      for (int mi = 0; mi < 4; ++mi) {
        int row = wr * 64 + mi * 16 + li;
        af[mi] = *(const s16x8*)(sA + row * 64 + ((ks * 32 + lg * 8) ^ ((row & 7) << 3)));
      }
#pragma unroll
      for (int ni = 0; ni < 4; ++ni) {
        int row = wc * 64 + ni * 16 + li;
        bfr[ni] = *(const s16x8*)(sB + row * 64 + ((ks * 32 + lg * 8) ^ ((row & 7) << 3)));
      }
#pragma unroll
      for (int mi = 0; mi < 4; ++mi)
#pragma unroll
        for (int ni = 0; ni < 4; ++ni)
          acc[mi][ni] = __builtin_amdgcn_mfma_f32_16x16x32_bf16(af[mi], bfr[ni], acc[mi][ni], 0, 0, 0);
    }
    __syncthreads();
  }
  float rk[4]; bool valid[4];
#pragma unroll
  for (int ni = 0; ni < 4; ++ni) {
    int gcol = b * 1024 + kt_ * 128 + wc * 64 + ni * 16 + li;
    rk[ni] = 1.0f / fmaxf(sqrtf(kssq[gcol]), 1e-8f);
    valid[ni] = (pad[gcol] == 0);
  }
#pragma unroll
  for (int mi = 0; mi < 4; ++mi) {
#pragma unroll
    for (int r = 0; r < 4; ++r) {
      float v = -INFINITY;
#pragma unroll
      for (int ni = 0; ni < 4; ++ni)
        if (valid[ni]) v = fmaxf(v, acc[mi][ni][r] * rk[ni]);
#pragma unroll
      for (int off = 1; off < 16; off <<= 1) v = fmaxf(v, __shfl_xor(v, off, 64));
      if (li == 0) {
        int row = b * 1024 + qt * 128 + wr * 64 + mi * 16 + lg * 4 + r;
        unsigned e = fenc2(v);
        if (e) atomicMax(&umax[row], e);
      }
    }
  }
}

// ---------- tiny MLP ----------
__global__ __launch_bounds__(256) void mlp_kernel(const unsigned* __restrict__ umax,
                                                  const float* __restrict__ qssq,
                                                  const float* __restrict__ w1,
                                                  const float* __restrict__ b1,
                                                  const float* __restrict__ w2,
                                                  const float* __restrict__ b2,
                                                  float* __restrict__ out, int n) {
  int i = blockIdx.x * 256 + threadIdx.x;
  if (i >= n) return;
  float m = fdec2(umax[i]) / fmaxf(sqrtf(qssq[i]), 1e-8f);
  float s = b2[0];
#pragma unroll
  for (int j = 0; j < 16; ++j) s += w2[j] * fmaxf(m * w1[j] + b1[j], 0.f);
  out[i] = 1.f / (1.f + expf(-s));
}

// ---------- host ----------
extern "C" void kernel_launch(void* const* d_in, const int* in_sizes, int n_in,
                              void* d_out, int out_size, void* d_ws, size_t ws_size,
                              hipStream_t stream) {
  const float* image = (const float*)d_in[0];   // [16,32,32,768]
  const float* text  = (const float*)d_in[1];   // [16,1024,768]
  const int*   pad   = (const int*)d_in[2];     // [16,32,32]
  const float* Wq    = (const float*)d_in[3];
  const float* bq    = (const float*)d_in[4];
  const float* Wk    = (const float*)d_in[5];
  const float* bk    = (const float*)d_in[6];
  const float* W1    = (const float*)d_in[7];
  const float* b1    = (const float*)d_in[8];
  const float* W2    = (const float*)d_in[9];
  const float* b2    = (const float*)d_in[10];
  float* out = (float*)d_out;

  char* ws = (char*)d_ws;
  unsigned*       um  = (unsigned*)(ws);                    // 65536
  float*          qss = (float*)(ws + 65536);               // 65536
  float*          kss = (float*)(ws + 131072);              // 65536
  unsigned short* Wqb = (unsigned short*)(ws + 196608);     // 1179648
  unsigned short* Wkb = (unsigned short*)(ws + 1376256);    // 1179648
  unsigned short* Qh  = (unsigned short*)(ws + 2555904);    // 25165824
  unsigned short* Kh  = (unsigned short*)(ws + 27721728);   // 25165824

  // 1) weights -> bf16, zero um/qss/kss
  cvt2w<<<1152, 256, 0, stream>>>(Wq, Wk, Wqb, Wkb, um);
  // 2) both projections (fused f32->bf16 A-staging, prefetched), one dispatch
  proj<<<dim3(768, 1, 2), 256, 0, stream>>>(text, image, Wqb, Wkb, bq, bk, Qh, Kh, qss, kss);
  // 3) masked cosine scores + row max
  scores_max<<<1024, 256, 0, stream>>>(Qh, Kh, kss, pad, um);
  // 4) tiny MLP
  mlp_kernel<<<64, 256, 0, stream>>>(um, qss, W1, b1, W2, b2, out, 16384);
}